// Round 2
// baseline (1414.271 us; speedup 1.0000x reference)
//
#include <hip/hip_runtime.h>
#include <cstdint>
#include <cstddef>

#define BB 64
#define NN 4096

// ---------------------------------------------------------------------------
// Farthest point sampling, latency-optimized. One block per batch.
// - All points staged to LDS once; centroid coords read via LDS broadcast
//   (removes the per-iteration global-load latency).
// - Per-thread best tracked as (float dist, int idx) with strict '>' in
//   increasing-i order => numpy argmax first-index tie-break preserved.
// - Exactly ONE __syncthreads per iteration: per-wave maxima go into
//   parity-double-buffered LDS slots; every thread then redundantly reduces
//   the NW values and decodes `far` locally.
// - Distance uses forced IEEE ops ((dx*dx + dy*dy) + dz*dz, no contraction)
//   to match the numpy reference bit-for-bit.
// ---------------------------------------------------------------------------
template<int T, int NPER>
__global__ __launch_bounds__(T) void fps_kernel(
    const float* __restrict__ xyz, int n, int npoint,
    int* __restrict__ idx_out, float* __restrict__ sel_xyz)
{
  constexpr int NW = T / 64;
  __shared__ float pts[T * NPER * 3];
  __shared__ unsigned long long sh_pk[2][NW];

  const int b = blockIdx.x;
  const int tid = threadIdx.x;
  const float* xb = xyz + (size_t)b * n * 3;

  // stage points into LDS (coalesced)
  for (int i = tid; i < n * 3; i += T) pts[i] = xb[i];

  float dst[NPER];
#pragma unroll
  for (int k = 0; k < NPER; ++k) dst[k] = 1e10f;

  __syncthreads();

  int far = 0;
  float cx = pts[0], cy = pts[1], cz = pts[2];

  for (int it = 0; it < npoint; ++it) {
    if (tid == 0) {
      idx_out[b * npoint + it] = far;
      if (sel_xyz) {
        sel_xyz[(b * npoint + it) * 3 + 0] = cx;
        sel_xyz[(b * npoint + it) * 3 + 1] = cy;
        sel_xyz[(b * npoint + it) * 3 + 2] = cz;
      }
    }

    float bestd = -1.0f;
    int   besti = 0;
#pragma unroll
    for (int k = 0; k < NPER; ++k) {
      int i = k * T + tid;
      float dx = pts[i*3+0] - cx, dy = pts[i*3+1] - cy, dz = pts[i*3+2] - cz;
      // ((dx*dx + dy*dy) + dz*dz) with forced IEEE ops (no contraction)
      float dd = __fadd_rn(__fadd_rn(__fmul_rn(dx, dx), __fmul_rn(dy, dy)),
                           __fmul_rn(dz, dz));
      float nd = fminf(dst[k], dd);
      dst[k] = nd;
      if (i < n && nd > bestd) { bestd = nd; besti = i; }
    }

    unsigned long long pk = (bestd >= 0.0f)
        ? (((unsigned long long)__float_as_uint(bestd) << 32)
           | (unsigned long long)(0xFFFFFFFFu - (unsigned)besti))
        : 0ull;

    // 64-lane butterfly max
#pragma unroll
    for (int o = 32; o > 0; o >>= 1) {
      unsigned long long other = __shfl_xor(pk, o);
      if (other > pk) pk = other;
    }
    if ((tid & 63) == 0) sh_pk[it & 1][tid >> 6] = pk;
    __syncthreads();

    unsigned long long m = sh_pk[it & 1][0];
#pragma unroll
    for (int w = 1; w < NW; ++w) {
      unsigned long long v = sh_pk[it & 1][w];
      if (v > m) m = v;
    }
    far = (int)(0xFFFFFFFFu - (unsigned)(m & 0xFFFFFFFFull));
    cx = pts[far*3+0]; cy = pts[far*3+1]; cz = pts[far*3+2];
  }
}

// ---------------------------------------------------------------------------
// Confidence MLP for ALL points: conf = sigmoid(relu(x@cw1+cb1)@cw2+cb2)
// ---------------------------------------------------------------------------
__global__ __launch_bounds__(256) void conf_kernel(
    const float* __restrict__ x,
    const float* __restrict__ cw1, const float* __restrict__ cb1,
    const float* __restrict__ cw2, const float* __restrict__ cb2,
    float* __restrict__ conf_out, int total)
{
  int i = blockIdx.x * 256 + threadIdx.x;
  if (i >= total) return;
  float x0 = x[i*3+0], x1 = x[i*3+1], x2 = x[i*3+2];
  float acc = cb2[0];
#pragma unroll
  for (int j = 0; j < 64; ++j) {
    float h = x0*cw1[j] + x1*cw1[64+j] + x2*cw1[128+j] + cb1[j];
    h = fmaxf(h, 0.f);
    acc += h * cw2[j];
  }
  conf_out[i] = 1.f / (1.f + expf(-acc));
}

// ---------------------------------------------------------------------------
// Fused per-sampled-point feature pipeline: conf -> l1(64) -> l2(256) = nf1.
// One 64-lane wave per sampled point, 4 waves per block.
// ---------------------------------------------------------------------------
__global__ __launch_bounds__(256) void selfeat_kernel(
    const float* __restrict__ x, const int* __restrict__ idx1,
    const float* __restrict__ cw1, const float* __restrict__ cb1,
    const float* __restrict__ cw2, const float* __restrict__ cb2,
    const float* __restrict__ w1, const float* __restrict__ b1,
    const float* __restrict__ w2, const float* __restrict__ b2,
    float* __restrict__ nf1)
{
  int wid  = threadIdx.x >> 6;
  int lane = threadIdx.x & 63;
  int gw   = blockIdx.x * 4 + wid;           // point slot in [0, B*500)
  int b = gw / 500, s = gw % 500;
  int p = idx1[b*500 + s];
  const float* xp = x + ((size_t)b * NN + p) * 3;
  float x0 = xp[0], x1 = xp[1], x2 = xp[2];

  // conf
  float h = fmaxf(x0*cw1[lane] + x1*cw1[64+lane] + x2*cw1[128+lane] + cb1[lane], 0.f);
  float part = h * cw2[lane];
#pragma unroll
  for (int o = 32; o > 0; o >>= 1) part += __shfl_xor(part, o);
  float conf = 1.f / (1.f + expf(-(part + cb2[0])));

  // l1 (64)
  float l1v = fmaxf(conf*w1[lane] + x0*w1[64+lane] + x1*w1[128+lane]
                    + x2*w1[192+lane] + b1[lane], 0.f);
  __shared__ float l1s[4][64];
  l1s[wid][lane] = l1v;
  __syncthreads();

  // l2 (256): each lane computes 4 outputs
  float a0 = b2[lane], a1 = b2[64+lane], a2 = b2[128+lane], a3 = b2[192+lane];
#pragma unroll
  for (int k = 0; k < 64; ++k) {
    float lv = l1s[wid][k];
    const float* wr = w2 + k*256;
    a0 += lv * wr[lane];
    a1 += lv * wr[64+lane];
    a2 += lv * wr[128+lane];
    a3 += lv * wr[192+lane];
  }
  float* o = nf1 + (size_t)gw * 256;
  o[lane]      = fmaxf(a0, 0.f);
  o[64+lane]   = fmaxf(a1, 0.f);
  o[128+lane]  = fmaxf(a2, 0.f);
  o[192+lane]  = fmaxf(a3, 0.f);
}

// ---------------------------------------------------------------------------
// Generic f32 GEMM: C[M,N](ldc) = act(A[M,K] @ W[K,N] + bias), 64x64 tile.
// ---------------------------------------------------------------------------
__global__ __launch_bounds__(256) void gemm_kernel(
    const float* __restrict__ A, const float* __restrict__ W,
    const float* __restrict__ bias, float* __restrict__ C,
    int M, int K, int Nc, int ldc, int act)
{
  __shared__ float As[16][68];
  __shared__ float Ws[16][64];
  int tid = threadIdx.x;
  int tx = tid & 15, ty = tid >> 4;
  int brow = blockIdx.y * 64, bcol = blockIdx.x * 64;

  float acc[4][4] = {{0.f}};

  for (int k0 = 0; k0 < K; k0 += 16) {
    {
      int m  = tid >> 4;
      int kk = tid & 15;
#pragma unroll
      for (int q = 0; q < 4; ++q) {
        int mm = m + q*16;
        float v = 0.f;
        if (k0 + kk < K) v = A[(size_t)(brow+mm)*K + k0 + kk];
        As[kk][mm] = v;
      }
      int kr = tid >> 6;
      int nn = tid & 63;
#pragma unroll
      for (int q = 0; q < 4; ++q) {
        int kkk = kr + q*4;
        float v = 0.f;
        if (k0 + kkk < K) v = W[(size_t)(k0+kkk)*Nc + bcol + nn];
        Ws[kkk][nn] = v;
      }
    }
    __syncthreads();
#pragma unroll
    for (int kk = 0; kk < 16; ++kk) {
      float a[4], bv[4];
#pragma unroll
      for (int i = 0; i < 4; ++i) a[i]  = As[kk][ty*4+i];
#pragma unroll
      for (int j = 0; j < 4; ++j) bv[j] = Ws[kk][tx*4+j];
#pragma unroll
      for (int i = 0; i < 4; ++i)
#pragma unroll
        for (int j = 0; j < 4; ++j) acc[i][j] += a[i]*bv[j];
    }
    __syncthreads();
  }

#pragma unroll
  for (int i = 0; i < 4; ++i) {
    int row = brow + ty*4 + i;
#pragma unroll
    for (int j = 0; j < 4; ++j) {
      int col = bcol + tx*4 + j;
      float v = acc[i][j] + bias[col];
      if (act) v = fmaxf(v, 0.f);
      C[(size_t)row*ldc + col] = v;
    }
  }
}

// copy (rows,3) xyz into first 3 columns of a (rows, ldc) matrix
__global__ __launch_bounds__(256) void copy_nx_kernel(
    const float* __restrict__ nx, float* __restrict__ dst, int rows, int ldc)
{
  int i = blockIdx.x * 256 + threadIdx.x;
  if (i >= rows * 3) return;
  int r = i / 3, c = i % 3;
  dst[(size_t)r*ldc + c] = nx[i];
}

// dst[b,s,c] = src[b, idx[b,s], c]
__global__ __launch_bounds__(256) void gather_kernel(
    const float* __restrict__ src, const int* __restrict__ idx,
    float* __restrict__ dst, int Bv, int Ss, int Sd, int C)
{
  int i = blockIdx.x * 256 + threadIdx.x;
  int total = Bv * Sd * C;
  if (i >= total) return;
  int c = i % C; int t = i / C; int s = t % Sd; int b = t / Sd;
  int p = idx[b*Sd + s];
  dst[i] = src[((size_t)b*Ss + p)*C + c];
}

// out[b,n] = max_s l8[b,s,n], s in [0,125)
__global__ __launch_bounds__(256) void maxpool_kernel(
    const float* __restrict__ l8, float* __restrict__ out)
{
  int i = blockIdx.x * 256 + threadIdx.x;
  if (i >= BB * 512) return;
  int b = i >> 9, n = i & 511;
  const float* p = l8 + (size_t)b * 125 * 512 + n;
  float m = p[0];
  for (int s = 1; s < 125; ++s) m = fmaxf(m, p[(size_t)s * 512]);
  out[(size_t)b*512 + n] = m;
}

// ---------------------------------------------------------------------------
extern "C" void kernel_launch(void* const* d_in, const int* in_sizes, int n_in,
                              void* d_out, int out_size, void* d_ws, size_t ws_size,
                              hipStream_t stream)
{
  const float* x    = (const float*)d_in[0];
  const float* cw1  = (const float*)d_in[1];
  const float* cb1  = (const float*)d_in[2];
  const float* cw2  = (const float*)d_in[3];
  const float* cb2  = (const float*)d_in[4];
  const float* w1   = (const float*)d_in[5];
  const float* b1   = (const float*)d_in[6];
  const float* w2   = (const float*)d_in[7];
  const float* b2   = (const float*)d_in[8];
  const float* w3   = (const float*)d_in[9];
  const float* b3   = (const float*)d_in[10];
  const float* w4   = (const float*)d_in[11];
  const float* b4   = (const float*)d_in[12];
  const float* w5   = (const float*)d_in[13];
  const float* b5   = (const float*)d_in[14];
  const float* w6   = (const float*)d_in[15];
  const float* b6   = (const float*)d_in[16];
  const float* pc1w = (const float*)d_in[17];
  const float* pc1b = (const float*)d_in[18];
  const float* pc2w = (const float*)d_in[19];
  const float* pc2b = (const float*)d_in[20];

  float* out      = (float*)d_out;          // (64,512)
  float* conf_out = out + 64*512;           // (64,4096,1)

  // ---- workspace carve-up (reused regions) ----
  char* ws = (char*)d_ws;
  size_t off = 0;
  auto alloc = [&](size_t bytes) -> void* {
    void* p = ws + off;
    off = (off + bytes + 255) & ~(size_t)255;
    return p;
  };
  int*   idx1 = (int*)  alloc((size_t)BB*500*4);
  int*   idx2 = (int*)  alloc((size_t)BB*250*4);
  int*   idx3 = (int*)  alloc((size_t)BB*125*4);
  float* nx1  = (float*)alloc((size_t)BB*500*3*4);
  float* nx2  = (float*)alloc((size_t)BB*250*3*4);
  float* R1   = (float*)alloc((size_t)BB*500*384*4);  // nf1 -> l5 -> l8
  float* R2   = (float*)alloc((size_t)BB*500*259*4);  // cat1 -> nf2 -> l7
  float* R3   = (float*)alloc((size_t)BB*500*256*4);  // l4 -> cat2
  float* S1   = (float*)alloc((size_t)BB*125*384*4);  // nf3
  (void)ws_size; (void)in_sizes; (void)n_in; (void)out_size;

  // ---- FPS chain (sequential dependencies) ----
  fps_kernel<512, 8><<<BB, 512, 0, stream>>>(x,   NN,  500, idx1, nx1);
  fps_kernel<512, 1><<<BB, 512, 0, stream>>>(nx1, 500, 250, idx2, nx2);
  fps_kernel<256, 1><<<BB, 256, 0, stream>>>(nx2, 250, 125, idx3, nullptr);

  // ---- conf for all points (output 1) ----
  conf_kernel<<<(BB*NN + 255)/256, 256, 0, stream>>>(x, cw1, cb1, cw2, cb2,
                                                     conf_out, BB*NN);

  // ---- fused conf/l1/l2 for the 32000 sampled points -> nf1 (R1) ----
  selfeat_kernel<<<BB*500/4, 256, 0, stream>>>(x, idx1, cw1, cb1, cw2, cb2,
                                               w1, b1, w2, b2, R1);

  // l3 = nf1 @ pc1w + pc1b  -> cat1 cols 3.. (R2, ldc=259)
  gemm_kernel<<<dim3(256/64, BB*500/64), 256, 0, stream>>>(
      R1, pc1w, pc1b, R2 + 3, BB*500, 256, 256, 259, 0);
  copy_nx_kernel<<<(BB*500*3 + 255)/256, 256, 0, stream>>>(nx1, R2, BB*500, 259);

  // l4 = relu(cat1 @ w3 + b3) -> R3 (32000 x 256)
  gemm_kernel<<<dim3(256/64, BB*500/64), 256, 0, stream>>>(
      R2, w3, b3, R3, BB*500, 259, 256, 256, 1);

  // l5 = relu(l4 @ w4 + b4) -> R1 (32000 x 384)
  gemm_kernel<<<dim3(384/64, BB*500/64), 256, 0, stream>>>(
      R3, w4, b4, R1, BB*500, 256, 384, 384, 1);

  // nf2 = l5[idx2] -> R2 (16000 x 384)
  gather_kernel<<<(BB*250*384 + 255)/256, 256, 0, stream>>>(
      R1, idx2, R2, BB, 500, 250, 384);

  // l6 = nf2 @ pc2w + pc2b -> cat2 cols 3.. (R3, ldc=387)
  gemm_kernel<<<dim3(384/64, BB*250/64), 256, 0, stream>>>(
      R2, pc2w, pc2b, R3 + 3, BB*250, 384, 384, 387, 0);
  copy_nx_kernel<<<(BB*250*3 + 255)/256, 256, 0, stream>>>(nx2, R3, BB*250, 387);

  // l7 = relu(cat2 @ w5 + b5) -> R2 (16000 x 384)
  gemm_kernel<<<dim3(384/64, BB*250/64), 256, 0, stream>>>(
      R3, w5, b5, R2, BB*250, 387, 384, 384, 1);

  // nf3 = l7[idx3] -> S1 (8000 x 384)
  gather_kernel<<<(BB*125*384 + 255)/256, 256, 0, stream>>>(
      R2, idx3, S1, BB, 250, 125, 384);

  // l8 = relu(nf3 @ w6 + b6) -> R1 (8000 x 512)
  gemm_kernel<<<dim3(512/64, BB*125/64), 256, 0, stream>>>(
      S1, w6, b6, R1, BB*125, 384, 512, 512, 1);

  // out = max over s
  maxpool_kernel<<<(BB*512 + 255)/256, 256, 0, stream>>>(R1, out);
}

// Round 3
// 1000.351 us; speedup vs baseline: 1.4138x; 1.4138x over previous
//
#include <hip/hip_runtime.h>
#include <cstdint>
#include <cstddef>

#define BB 64
#define NN 4096

// ---------------------------------------------------------------------------
// Forced-IEEE squared distance ((dx*dx + dy*dy) + dz*dz), matching numpy's
// op order with no FMA contraction -> argmax selection is bit-exact.
// ---------------------------------------------------------------------------
__device__ __forceinline__ float sqdist(float px, float py, float pz,
                                        float cx, float cy, float cz) {
  float dx = px - cx, dy = py - cy, dz = pz - cz;
  return __fadd_rn(__fadd_rn(__fmul_rn(dx, dx), __fmul_rn(dy, dy)),
                   __fmul_rn(dz, dz));
}

__device__ __forceinline__ unsigned long long u64max(unsigned long long a,
                                                    unsigned long long b) {
  return a > b ? a : b;
}

// ---------------------------------------------------------------------------
// Single-wave FPS (n <= NPER*64). Points in registers; LDS copy only for the
// uniform-address centroid broadcast. No barriers (caller: only wave 0 runs).
// Tie-break = lowest index via (dist_bits<<32)|(~idx) packing + max.
// ---------------------------------------------------------------------------
template<int NPER>
__device__ void fps_wave(const float* __restrict__ xb, int n, int npoint,
                         int* __restrict__ idx_out, float* __restrict__ sel_out,
                         float* pts /* LDS, >= NPER*64*3 floats */)
{
  const int lane = threadIdx.x;                    // caller ensures < 64
  for (int i = lane; i < n * 3; i += 64) pts[i] = xb[i];
  for (int i = n * 3 + lane; i < NPER * 64 * 3; i += 64) pts[i] = 0.f;
  // same-wave LDS RAW: in-order per wave; compiler must preserve (may alias)

  float px[NPER], py[NPER], pz[NPER], dst[NPER];
#pragma unroll
  for (int k = 0; k < NPER; ++k) {
    int i = k * 64 + lane;
    px[k] = pts[i*3+0]; py[k] = pts[i*3+1]; pz[k] = pts[i*3+2];
    dst[k] = 1e10f;
  }

  int far = 0;
  float cx = pts[0], cy = pts[1], cz = pts[2];

  for (int it = 0; it < npoint; ++it) {
    if (lane == 0) {
      idx_out[it] = far;
      if (sel_out) {
        sel_out[it*3+0] = cx; sel_out[it*3+1] = cy; sel_out[it*3+2] = cz;
      }
    }
    float bestd = -1.f; int besti = 0;
#pragma unroll
    for (int k = 0; k < NPER; ++k) {
      int i = k * 64 + lane;
      float nd = fminf(dst[k], sqdist(px[k], py[k], pz[k], cx, cy, cz));
      dst[k] = nd;
      if (i < n && nd > bestd) { bestd = nd; besti = i; }
    }
    unsigned long long pk =
        ((unsigned long long)__float_as_uint(bestd) << 32)
      | (unsigned long long)(0xFFFFFFFFu - (unsigned)besti);
#pragma unroll
    for (int o = 32; o > 0; o >>= 1) {
      unsigned long long t = __shfl_xor(pk, o);
      if (t > pk) pk = t;
    }
    far = (int)(0xFFFFFFFFu - (unsigned)(pk & 0xFFFFFFFFull));
    cx = pts[far*3+0]; cy = pts[far*3+1]; cz = pts[far*3+2];
  }
}

// ---------------------------------------------------------------------------
// Kernel A: blocks [0,64) = FPS1 (256 thr, 16 pts/thread in REGISTERS, one
// barrier/iter, LDS centroid broadcast); blocks [64,..) = conf MLP for all
// B*N points (independent of FPS -> hidden under FPS1's latency-bound tail).
// ---------------------------------------------------------------------------
__global__ __launch_bounds__(256) void fps1_conf_kernel(
    const float* __restrict__ x,
    const float* __restrict__ cw1, const float* __restrict__ cb1,
    const float* __restrict__ cw2, const float* __restrict__ cb2,
    int* __restrict__ idx1, float* __restrict__ nx1,
    float* __restrict__ conf_out)
{
  if (blockIdx.x >= BB) {
    int i = (blockIdx.x - BB) * 256 + threadIdx.x;
    if (i < BB * NN) {
      float x0 = x[i*3+0], x1 = x[i*3+1], x2 = x[i*3+2];
      float acc = cb2[0];
#pragma unroll
      for (int j = 0; j < 64; ++j) {
        float h = fmaxf(x0*cw1[j] + x1*cw1[64+j] + x2*cw1[128+j] + cb1[j], 0.f);
        acc += h * cw2[j];
      }
      conf_out[i] = 1.f / (1.f + expf(-acc));
    }
    return;
  }

  constexpr int NPER = NN / 256;   // 16
  __shared__ float pts[NN * 3];
  __shared__ unsigned long long sh_pk[2][4];
  const int b = blockIdx.x, tid = threadIdx.x;
  const float* xb = x + (size_t)b * NN * 3;

  for (int i = tid; i < NN * 3; i += 256) pts[i] = xb[i];
  __syncthreads();

  float px[NPER], py[NPER], pz[NPER], dst[NPER];
#pragma unroll
  for (int k = 0; k < NPER; ++k) {
    int i = k * 256 + tid;
    px[k] = pts[i*3+0]; py[k] = pts[i*3+1]; pz[k] = pts[i*3+2];
    dst[k] = 1e10f;
  }

  int far = 0;
  float cx = pts[0], cy = pts[1], cz = pts[2];

  for (int it = 0; it < 500; ++it) {
    if (tid == 0) {
      idx1[b*500 + it] = far;
      nx1[(b*500+it)*3+0] = cx; nx1[(b*500+it)*3+1] = cy; nx1[(b*500+it)*3+2] = cz;
    }
    float bestd = -1.f; int besti = 0;
#pragma unroll
    for (int k = 0; k < NPER; ++k) {
      int i = k * 256 + tid;
      float nd = fminf(dst[k], sqdist(px[k], py[k], pz[k], cx, cy, cz));
      dst[k] = nd;
      if (nd > bestd) { bestd = nd; besti = i; }   // 4096 = 16*256, no guard
    }
    unsigned long long pk =
        ((unsigned long long)__float_as_uint(bestd) << 32)
      | (unsigned long long)(0xFFFFFFFFu - (unsigned)besti);
#pragma unroll
    for (int o = 32; o > 0; o >>= 1) {
      unsigned long long t = __shfl_xor(pk, o);
      if (t > pk) pk = t;
    }
    if ((tid & 63) == 0) sh_pk[it & 1][tid >> 6] = pk;
    __syncthreads();
    unsigned long long m = u64max(u64max(sh_pk[it&1][0], sh_pk[it&1][1]),
                                  u64max(sh_pk[it&1][2], sh_pk[it&1][3]));
    far = (int)(0xFFFFFFFFu - (unsigned)(m & 0xFFFFFFFFull));
    cx = pts[far*3+0]; cy = pts[far*3+1]; cz = pts[far*3+2];
  }
}

// ---------------------------------------------------------------------------
// Kernel B: blocks [0,64) = FPS2 single-wave (waves 1..3 exit; no barriers on
// that path); blocks [64,..) = selfeat (fused conf->l1->l2 for sampled pts).
// ---------------------------------------------------------------------------
__global__ __launch_bounds__(256) void fps2_selfeat_kernel(
    const float* __restrict__ x, const float* __restrict__ nx1,
    const int* __restrict__ idx1,
    const float* __restrict__ cw1, const float* __restrict__ cb1,
    const float* __restrict__ cw2, const float* __restrict__ cb2,
    const float* __restrict__ w1, const float* __restrict__ b1,
    const float* __restrict__ w2, const float* __restrict__ b2,
    int* __restrict__ idx2, float* __restrict__ nx2,
    float* __restrict__ nf1)
{
  __shared__ float pts[8 * 64 * 3];     // fps2 staging (6 KB)
  __shared__ float l1s[4][64];          // selfeat

  if (blockIdx.x < BB) {
    if (threadIdx.x >= 64) return;
    int b = blockIdx.x;
    fps_wave<8>(nx1 + (size_t)b*500*3, 500, 250,
                idx2 + b*250, nx2 + (size_t)b*250*3, pts);
    return;
  }

  int wid  = threadIdx.x >> 6;
  int lane = threadIdx.x & 63;
  int gw   = (blockIdx.x - BB) * 4 + wid;      // [0, B*500)
  int b = gw / 500, s = gw % 500;
  int p = idx1[b*500 + s];
  const float* xp = x + ((size_t)b * NN + p) * 3;
  float x0 = xp[0], x1 = xp[1], x2 = xp[2];

  float h = fmaxf(x0*cw1[lane] + x1*cw1[64+lane] + x2*cw1[128+lane] + cb1[lane], 0.f);
  float part = h * cw2[lane];
#pragma unroll
  for (int o = 32; o > 0; o >>= 1) part += __shfl_xor(part, o);
  float conf = 1.f / (1.f + expf(-(part + cb2[0])));

  float l1v = fmaxf(conf*w1[lane] + x0*w1[64+lane] + x1*w1[128+lane]
                    + x2*w1[192+lane] + b1[lane], 0.f);
  l1s[wid][lane] = l1v;
  __syncthreads();

  float a0 = b2[lane], a1 = b2[64+lane], a2 = b2[128+lane], a3 = b2[192+lane];
#pragma unroll
  for (int k = 0; k < 64; ++k) {
    float lv = l1s[wid][k];
    const float* wr = w2 + k*256;
    a0 += lv * wr[lane];
    a1 += lv * wr[64+lane];
    a2 += lv * wr[128+lane];
    a3 += lv * wr[192+lane];
  }
  float* o = nf1 + (size_t)gw * 256;
  o[lane]     = fmaxf(a0, 0.f);
  o[64+lane]  = fmaxf(a1, 0.f);
  o[128+lane] = fmaxf(a2, 0.f);
  o[192+lane] = fmaxf(a3, 0.f);
}

// ---------------------------------------------------------------------------
// f32 GEMM body: C[M,N](ldc) = act(A[M,K] @ W[K,N] + bias), 64x64 tile.
// ---------------------------------------------------------------------------
__device__ __forceinline__ void gemm_body(
    const float* __restrict__ A, const float* __restrict__ W,
    const float* __restrict__ bias, float* __restrict__ C,
    int M, int K, int Nc, int ldc, int act, int bx, int by,
    float (&As)[16][68], float (&Ws)[16][64])
{
  int tid = threadIdx.x;
  int tx = tid & 15, ty = tid >> 4;
  int brow = by * 64, bcol = bx * 64;

  float acc[4][4] = {{0.f}};

  for (int k0 = 0; k0 < K; k0 += 16) {
    {
      int m  = tid >> 4;
      int kk = tid & 15;
#pragma unroll
      for (int q = 0; q < 4; ++q) {
        int mm = m + q*16;
        float v = 0.f;
        if (k0 + kk < K) v = A[(size_t)(brow+mm)*K + k0 + kk];
        As[kk][mm] = v;
      }
      int kr = tid >> 6;
      int nn = tid & 63;
#pragma unroll
      for (int q = 0; q < 4; ++q) {
        int kkk = kr + q*4;
        float v = 0.f;
        if (k0 + kkk < K) v = W[(size_t)(k0+kkk)*Nc + bcol + nn];
        Ws[kkk][nn] = v;
      }
    }
    __syncthreads();
#pragma unroll
    for (int kk = 0; kk < 16; ++kk) {
      float a[4], bv[4];
#pragma unroll
      for (int i = 0; i < 4; ++i) a[i]  = As[kk][ty*4+i];
#pragma unroll
      for (int j = 0; j < 4; ++j) bv[j] = Ws[kk][tx*4+j];
#pragma unroll
      for (int i = 0; i < 4; ++i)
#pragma unroll
        for (int j = 0; j < 4; ++j) acc[i][j] += a[i]*bv[j];
    }
    __syncthreads();
  }

#pragma unroll
  for (int i = 0; i < 4; ++i) {
    int row = brow + ty*4 + i;
#pragma unroll
    for (int j = 0; j < 4; ++j) {
      int col = bcol + tx*4 + j;
      float v = acc[i][j] + bias[col];
      if (act) v = fmaxf(v, 0.f);
      C[(size_t)row*ldc + col] = v;
    }
  }
}

// plain GEMM (1D grid: blk = by*nbx + bx)
__global__ __launch_bounds__(256) void gemm_kernel(
    const float* __restrict__ A, const float* __restrict__ W,
    const float* __restrict__ bias, float* __restrict__ C,
    int M, int K, int Nc, int ldc, int act)
{
  __shared__ float As[16][68];
  __shared__ float Ws[16][64];
  int nbx = Nc >> 6;
  gemm_body(A, W, bias, C, M, K, Nc, ldc, act,
            blockIdx.x % nbx, blockIdx.x / nbx, As, Ws);
}

// GEMM + trailing blocks copy (rows,3) xyz into first 3 cols of C's matrix
__global__ __launch_bounds__(256) void gemm_copy_kernel(
    const float* __restrict__ A, const float* __restrict__ W,
    const float* __restrict__ bias, float* __restrict__ C,
    int M, int K, int Nc, int ldc, int act,
    const float* __restrict__ nx, float* __restrict__ nxdst, int nrows,
    int gemm_blocks)
{
  __shared__ float As[16][68];
  __shared__ float Ws[16][64];
  if ((int)blockIdx.x < gemm_blocks) {
    int nbx = Nc >> 6;
    gemm_body(A, W, bias, C, M, K, Nc, ldc, act,
              blockIdx.x % nbx, blockIdx.x / nbx, As, Ws);
  } else {
    int i = ((int)blockIdx.x - gemm_blocks) * 256 + threadIdx.x;
    if (i < nrows * 3) {
      int r = i / 3, c = i % 3;
      nxdst[(size_t)r * ldc + c] = nx[i];
    }
  }
}

// blocks [0,64) = FPS3 single-wave; blocks [64,..) = GEMM (l4)
__global__ __launch_bounds__(256) void fps3_gemm_kernel(
    const float* __restrict__ nx2, int* __restrict__ idx3,
    const float* __restrict__ A, const float* __restrict__ W,
    const float* __restrict__ bias, float* __restrict__ C,
    int M, int K, int Nc, int ldc, int act)
{
  __shared__ float As[16][68];
  __shared__ float Ws[16][64];
  __shared__ float pts[4 * 64 * 3];
  if (blockIdx.x < BB) {
    if (threadIdx.x >= 64) return;
    int b = blockIdx.x;
    fps_wave<4>(nx2 + (size_t)b*250*3, 250, 125, idx3 + b*125, nullptr, pts);
    return;
  }
  int blk = blockIdx.x - BB;
  int nbx = Nc >> 6;
  gemm_body(A, W, bias, C, M, K, Nc, ldc, act, blk % nbx, blk / nbx, As, Ws);
}

// dst[b,s,c] = src[b, idx[b,s], c]
__global__ __launch_bounds__(256) void gather_kernel(
    const float* __restrict__ src, const int* __restrict__ idx,
    float* __restrict__ dst, int Bv, int Ss, int Sd, int C)
{
  int i = blockIdx.x * 256 + threadIdx.x;
  int total = Bv * Sd * C;
  if (i >= total) return;
  int c = i % C; int t = i / C; int s = t % Sd; int b = t / Sd;
  int p = idx[b*Sd + s];
  dst[i] = src[((size_t)b*Ss + p)*C + c];
}

// out[b,n] = max_s l8[b,s,n], s in [0,125)
__global__ __launch_bounds__(256) void maxpool_kernel(
    const float* __restrict__ l8, float* __restrict__ out)
{
  int i = blockIdx.x * 256 + threadIdx.x;
  if (i >= BB * 512) return;
  int b = i >> 9, n = i & 511;
  const float* p = l8 + (size_t)b * 125 * 512 + n;
  float m = p[0];
  for (int s = 1; s < 125; ++s) m = fmaxf(m, p[(size_t)s * 512]);
  out[(size_t)b*512 + n] = m;
}

// ---------------------------------------------------------------------------
extern "C" void kernel_launch(void* const* d_in, const int* in_sizes, int n_in,
                              void* d_out, int out_size, void* d_ws, size_t ws_size,
                              hipStream_t stream)
{
  const float* x    = (const float*)d_in[0];
  const float* cw1  = (const float*)d_in[1];
  const float* cb1  = (const float*)d_in[2];
  const float* cw2  = (const float*)d_in[3];
  const float* cb2  = (const float*)d_in[4];
  const float* w1   = (const float*)d_in[5];
  const float* b1   = (const float*)d_in[6];
  const float* w2   = (const float*)d_in[7];
  const float* b2   = (const float*)d_in[8];
  const float* w3   = (const float*)d_in[9];
  const float* b3   = (const float*)d_in[10];
  const float* w4   = (const float*)d_in[11];
  const float* b4   = (const float*)d_in[12];
  const float* w5   = (const float*)d_in[13];
  const float* b5   = (const float*)d_in[14];
  const float* w6   = (const float*)d_in[15];
  const float* b6   = (const float*)d_in[16];
  const float* pc1w = (const float*)d_in[17];
  const float* pc1b = (const float*)d_in[18];
  const float* pc2w = (const float*)d_in[19];
  const float* pc2b = (const float*)d_in[20];

  float* out      = (float*)d_out;          // (64,512)
  float* conf_out = out + 64*512;           // (64,4096,1)

  char* ws = (char*)d_ws;
  size_t off = 0;
  auto alloc = [&](size_t bytes) -> void* {
    void* p = ws + off;
    off = (off + bytes + 255) & ~(size_t)255;
    return p;
  };
  int*   idx1 = (int*)  alloc((size_t)BB*500*4);
  int*   idx2 = (int*)  alloc((size_t)BB*250*4);
  int*   idx3 = (int*)  alloc((size_t)BB*125*4);
  float* nx1  = (float*)alloc((size_t)BB*500*3*4);
  float* nx2  = (float*)alloc((size_t)BB*250*3*4);
  float* R1   = (float*)alloc((size_t)BB*500*384*4);  // nf1 -> l5 -> l8
  float* R2   = (float*)alloc((size_t)BB*500*259*4);  // cat1 -> nf2 -> l7
  float* R3   = (float*)alloc((size_t)BB*500*256*4);  // l4 -> cat2
  float* S1   = (float*)alloc((size_t)BB*125*384*4);  // nf3
  (void)ws_size; (void)in_sizes; (void)n_in; (void)out_size;

  // A: FPS1 + conf (conf hidden under FPS1)
  fps1_conf_kernel<<<BB + (BB*NN + 255)/256, 256, 0, stream>>>(
      x, cw1, cb1, cw2, cb2, idx1, nx1, conf_out);

  // B: FPS2 + selfeat (selfeat hidden under FPS2)
  fps2_selfeat_kernel<<<BB + BB*500/4, 256, 0, stream>>>(
      x, nx1, idx1, cw1, cb1, cw2, cb2, w1, b1, w2, b2, idx2, nx2, R1);

  // C: l3 = nf1 @ pc1w + pc1b -> cat1 cols 3.. ; + copy nx1 into cols 0..2
  {
    int gb = (256/64) * (BB*500/64);              // 2000
    int cb = (BB*500*3 + 255)/256;                // 375
    gemm_copy_kernel<<<gb + cb, 256, 0, stream>>>(
        R1, pc1w, pc1b, R2 + 3, BB*500, 256, 256, 259, 0,
        nx1, R2, BB*500, gb);
  }

  // D: FPS3 + l4 = relu(cat1 @ w3 + b3) (fps3 hidden under l4)
  fps3_gemm_kernel<<<BB + (256/64)*(BB*500/64), 256, 0, stream>>>(
      nx2, idx3, R2, w3, b3, R3, BB*500, 259, 256, 256, 1);

  // l5 = relu(l4 @ w4 + b4) -> R1 (32000 x 384)
  gemm_kernel<<<(384/64)*(BB*500/64), 256, 0, stream>>>(
      R3, w4, b4, R1, BB*500, 256, 384, 384, 1);

  // nf2 = l5[idx2] -> R2 (16000 x 384)
  gather_kernel<<<(BB*250*384 + 255)/256, 256, 0, stream>>>(
      R1, idx2, R2, BB, 500, 250, 384);

  // l6 = nf2 @ pc2w + pc2b -> cat2 cols 3.. ; + copy nx2 into cols 0..2
  {
    int gb = (384/64) * (BB*250/64);              // 1500
    int cb = (BB*250*3 + 255)/256;                // 188
    gemm_copy_kernel<<<gb + cb, 256, 0, stream>>>(
        R2, pc2w, pc2b, R3 + 3, BB*250, 384, 384, 387, 0,
        nx2, R3, BB*250, gb);
  }

  // l7 = relu(cat2 @ w5 + b5) -> R2 (16000 x 384)
  gemm_kernel<<<(384/64)*(BB*250/64), 256, 0, stream>>>(
      R3, w5, b5, R2, BB*250, 387, 384, 384, 1);

  // nf3 = l7[idx3] -> S1 (8000 x 384)
  gather_kernel<<<(BB*125*384 + 255)/256, 256, 0, stream>>>(
      R2, idx3, S1, BB, 250, 125, 384);

  // l8 = relu(nf3 @ w6 + b6) -> R1 (8000 x 512)
  gemm_kernel<<<(512/64)*(BB*125/64), 256, 0, stream>>>(
      S1, w6, b6, R1, BB*125, 384, 512, 512, 1);

  // out = max over s
  maxpool_kernel<<<(BB*512 + 255)/256, 256, 0, stream>>>(R1, out);
}

// Round 5
// 663.119 us; speedup vs baseline: 2.1328x; 1.5086x over previous
//
#include <hip/hip_runtime.h>
#include <hip/hip_bf16.h>
#include <cstdint>
#include <cstddef>

#define BB 64
#define NN 4096

typedef short bf16x8 __attribute__((ext_vector_type(8)));
typedef float f32x4 __attribute__((ext_vector_type(4)));
typedef unsigned short u16;
typedef unsigned int u32;

__device__ __forceinline__ u16 f2bf(float f) {
  __hip_bfloat16 h = __float2bfloat16(f);   // RTNE
  return *reinterpret_cast<u16*>(&h);
}
__device__ __forceinline__ float bf2f(u16 u) {
  return __uint_as_float((u32)u << 16);
}

// ---------------------------------------------------------------------------
// Forced-IEEE squared distance ((dx*dx + dy*dy) + dz*dz) -> bit-exact argmax.
// ---------------------------------------------------------------------------
__device__ __forceinline__ float sqdist(float px, float py, float pz,
                                        float cx, float cy, float cz) {
  float dx = px - cx, dy = py - cy, dz = pz - cz;
  return __fadd_rn(__fadd_rn(__fmul_rn(dx, dx), __fmul_rn(dy, dy)),
                   __fmul_rn(dz, dz));
}

__device__ __forceinline__ unsigned long long u64max(unsigned long long a,
                                                    unsigned long long b) {
  return a > b ? a : b;
}

// ---------------------------------------------------------------------------
// Single-wave FPS (n <= NPER*64). Points in registers; LDS only for the
// uniform-address centroid broadcast. No barriers (only wave 0 runs this).
// ---------------------------------------------------------------------------
template<int NPER>
__device__ void fps_wave(const float* __restrict__ xb, int n, int npoint,
                         int* __restrict__ idx_out, float* __restrict__ sel_out,
                         float* pts)
{
  const int lane = threadIdx.x;
  for (int i = lane; i < n * 3; i += 64) pts[i] = xb[i];
  for (int i = n * 3 + lane; i < NPER * 64 * 3; i += 64) pts[i] = 0.f;

  float px[NPER], py[NPER], pz[NPER], dst[NPER];
#pragma unroll
  for (int k = 0; k < NPER; ++k) {
    int i = k * 64 + lane;
    px[k] = pts[i*3+0]; py[k] = pts[i*3+1]; pz[k] = pts[i*3+2];
    dst[k] = 1e10f;
  }

  int far = 0;
  float cx = pts[0], cy = pts[1], cz = pts[2];

  for (int it = 0; it < npoint; ++it) {
    if (lane == 0) {
      idx_out[it] = far;
      if (sel_out) {
        sel_out[it*3+0] = cx; sel_out[it*3+1] = cy; sel_out[it*3+2] = cz;
      }
    }
    float bestd = -1.f; int besti = 0;
#pragma unroll
    for (int k = 0; k < NPER; ++k) {
      int i = k * 64 + lane;
      float nd = fminf(dst[k], sqdist(px[k], py[k], pz[k], cx, cy, cz));
      dst[k] = nd;
      if (i < n && nd > bestd) { bestd = nd; besti = i; }
    }
    unsigned long long pk =
        ((unsigned long long)__float_as_uint(bestd) << 32)
      | (unsigned long long)(0xFFFFFFFFu - (unsigned)besti);
#pragma unroll
    for (int o = 32; o > 0; o >>= 1) {
      unsigned long long t = __shfl_xor(pk, o);
      if (t > pk) pk = t;
    }
    far = (int)(0xFFFFFFFFu - (unsigned)(pk & 0xFFFFFFFFull));
    cx = pts[far*3+0]; cy = pts[far*3+1]; cz = pts[far*3+2];
  }
}

// ---------------------------------------------------------------------------
// Kernel A: [0,64) FPS1; [64,1088) conf MLP; [1088,1450) weight transpose+pad
// to bf16 via uint4 stores (16B per thread -> no cross-block dword sharing).
// Matrix switches land exactly on block boundaries.
// ---------------------------------------------------------------------------
__global__ __launch_bounds__(256) void fps1_conf_wtx_kernel(
    const float* __restrict__ x,
    const float* __restrict__ cw1, const float* __restrict__ cb1,
    const float* __restrict__ cw2, const float* __restrict__ cb2,
    const float* __restrict__ pc1w, const float* __restrict__ w3,
    const float* __restrict__ w4,  const float* __restrict__ pc2w,
    const float* __restrict__ w5,  const float* __restrict__ w6,
    int* __restrict__ idx1, float* __restrict__ nx1,
    float* __restrict__ conf_out,
    u16* wt1, u16* wt3, u16* wt4, u16* wtp2, u16* wt5, u16* wt6)
{
  if (blockIdx.x >= BB + 1024) {
    // ---- weight transpose + K-pad, 8 u16 per thread (one uint4 store) ----
    // slot ranges (in 8-elem units): wt1 [0,8192) wt3 [8192,17408)
    // wt4 [17408,29696) wtp2 [29696,48128) wt5 [48128,68096) wt6 [68096,92672)
    int s = (blockIdx.x - (BB + 1024)) * 256 + threadIdx.x;
    const float* src; u16* dst; int N, Ks, Kp;
    if      (s < 8192)  { dst=wt1;  src=pc1w; N=256; Ks=256; Kp=256; }
    else if (s < 17408) { dst=wt3;  src=w3;   N=256; Ks=259; Kp=288; s -= 8192; }
    else if (s < 29696) { dst=wt4;  src=w4;   N=384; Ks=256; Kp=256; s -= 17408; }
    else if (s < 48128) { dst=wtp2; src=pc2w; N=384; Ks=384; Kp=384; s -= 29696; }
    else if (s < 68096) { dst=wt5;  src=w5;   N=384; Ks=387; Kp=416; s -= 48128; }
    else                { dst=wt6;  src=w6;   N=512; Ks=384; Kp=384; s -= 68096; }
    int e0 = s * 8;
    int n = e0 / Kp, k0 = e0 % Kp;      // Kp % 8 == 0 -> row-constant n
    u16 tmp[8];
#pragma unroll
    for (int j = 0; j < 8; ++j) {
      int k = k0 + j;
      tmp[j] = f2bf(k < Ks ? src[k*N + n] : 0.f);
    }
    *(uint4*)&dst[e0] = *(const uint4*)tmp;
    return;
  }
  if (blockIdx.x >= BB) {
    // ---- conf MLP (exact f32, graded output 1) ----
    int i = (blockIdx.x - BB) * 256 + threadIdx.x;
    if (i < BB * NN) {
      float x0 = x[i*3+0], x1 = x[i*3+1], x2 = x[i*3+2];
      float acc = cb2[0];
#pragma unroll
      for (int j = 0; j < 64; ++j) {
        float h = fmaxf(x0*cw1[j] + x1*cw1[64+j] + x2*cw1[128+j] + cb1[j], 0.f);
        acc += h * cw2[j];
      }
      conf_out[i] = 1.f / (1.f + expf(-acc));
    }
    return;
  }

  // ---- FPS1: 256 thr, 16 pts/thread in registers, 1 barrier/iter ----
  constexpr int NPER = NN / 256;
  __shared__ float pts[NN * 3];
  __shared__ unsigned long long sh_pk[2][4];
  const int b = blockIdx.x, tid = threadIdx.x;
  const float* xb = x + (size_t)b * NN * 3;

  for (int i = tid; i < NN * 3; i += 256) pts[i] = xb[i];
  __syncthreads();

  float px[NPER], py[NPER], pz[NPER], dst[NPER];
#pragma unroll
  for (int k = 0; k < NPER; ++k) {
    int i = k * 256 + tid;
    px[k] = pts[i*3+0]; py[k] = pts[i*3+1]; pz[k] = pts[i*3+2];
    dst[k] = 1e10f;
  }

  int far = 0;
  float cx = pts[0], cy = pts[1], cz = pts[2];

  for (int it = 0; it < 500; ++it) {
    if (tid == 0) {
      idx1[b*500 + it] = far;
      nx1[(b*500+it)*3+0] = cx; nx1[(b*500+it)*3+1] = cy; nx1[(b*500+it)*3+2] = cz;
    }
    float bestd = -1.f; int besti = 0;
#pragma unroll
    for (int k = 0; k < NPER; ++k) {
      int i = k * 256 + tid;
      float nd = fminf(dst[k], sqdist(px[k], py[k], pz[k], cx, cy, cz));
      dst[k] = nd;
      if (nd > bestd) { bestd = nd; besti = i; }
    }
    unsigned long long pk =
        ((unsigned long long)__float_as_uint(bestd) << 32)
      | (unsigned long long)(0xFFFFFFFFu - (unsigned)besti);
#pragma unroll
    for (int o = 32; o > 0; o >>= 1) {
      unsigned long long t = __shfl_xor(pk, o);
      if (t > pk) pk = t;
    }
    if ((tid & 63) == 0) sh_pk[it & 1][tid >> 6] = pk;
    __syncthreads();
    unsigned long long m = u64max(u64max(sh_pk[it&1][0], sh_pk[it&1][1]),
                                  u64max(sh_pk[it&1][2], sh_pk[it&1][3]));
    far = (int)(0xFFFFFFFFu - (unsigned)(m & 0xFFFFFFFFull));
    cx = pts[far*3+0]; cy = pts[far*3+1]; cz = pts[far*3+2];
  }
}

// ---------------------------------------------------------------------------
// Kernel B: [0,64) FPS2 single-wave; [64,8064) selfeat -> nf1 bf16;
// [8064,8189) cat1-fix: write cat1 coords (cols 0..2) + zero pad (259..287).
// The l3 GEMM (NEXT launch) writes cols 3..258 -> no same-dword concurrency.
// ---------------------------------------------------------------------------
__global__ __launch_bounds__(256) void fps2_selfeat_cat1fix_kernel(
    const float* __restrict__ x, const float* __restrict__ nx1,
    const int* __restrict__ idx1,
    const float* __restrict__ cw1, const float* __restrict__ cb1,
    const float* __restrict__ cw2, const float* __restrict__ cb2,
    const float* __restrict__ w1, const float* __restrict__ b1,
    const float* __restrict__ w2, const float* __restrict__ b2,
    int* __restrict__ idx2, float* __restrict__ nx2,
    u16* __restrict__ nf1, u16* __restrict__ cat1)
{
  __shared__ float pts[8 * 64 * 3];
  __shared__ float l1s[4][64];

  if (blockIdx.x < BB) {
    if (threadIdx.x >= 64) return;
    int b = blockIdx.x;
    fps_wave<8>(nx1 + (size_t)b*500*3, 500, 250,
                idx2 + b*250, nx2 + (size_t)b*250*3, pts);
    return;
  }
  if (blockIdx.x >= BB + 8000) {
    int r = (blockIdx.x - (BB + 8000)) * 256 + threadIdx.x;  // < 32000
    u16* row = cat1 + (size_t)r * 288;
    row[0] = f2bf(nx1[r*3+0]);
    row[1] = f2bf(nx1[r*3+1]);
    row[2] = f2bf(nx1[r*3+2]);
#pragma unroll
    for (int c = 259; c < 288; ++c) row[c] = 0;
    return;
  }

  int wid  = threadIdx.x >> 6;
  int lane = threadIdx.x & 63;
  int gw   = (blockIdx.x - BB) * 4 + wid;      // [0, 32000)
  int b = gw / 500, s = gw % 500;
  int p = idx1[b*500 + s];
  const float* xp = x + ((size_t)b * NN + p) * 3;
  float x0 = xp[0], x1 = xp[1], x2 = xp[2];

  float h = fmaxf(x0*cw1[lane] + x1*cw1[64+lane] + x2*cw1[128+lane] + cb1[lane], 0.f);
  float part = h * cw2[lane];
#pragma unroll
  for (int o = 32; o > 0; o >>= 1) part += __shfl_xor(part, o);
  float conf = 1.f / (1.f + expf(-(part + cb2[0])));

  float l1v = fmaxf(conf*w1[lane] + x0*w1[64+lane] + x1*w1[128+lane]
                    + x2*w1[192+lane] + b1[lane], 0.f);
  l1s[wid][lane] = l1v;
  __syncthreads();

  float a0 = b2[lane], a1 = b2[64+lane], a2 = b2[128+lane], a3 = b2[192+lane];
#pragma unroll
  for (int k = 0; k < 64; ++k) {
    float lv = l1s[wid][k];
    const float* wr = w2 + k*256;
    a0 += lv * wr[lane];
    a1 += lv * wr[64+lane];
    a2 += lv * wr[128+lane];
    a3 += lv * wr[192+lane];
  }
  u16* o = nf1 + (size_t)gw * 256;
  o[lane]     = f2bf(fmaxf(a0, 0.f));
  o[64+lane]  = f2bf(fmaxf(a1, 0.f));
  o[128+lane] = f2bf(fmaxf(a2, 0.f));
  o[192+lane] = f2bf(fmaxf(a3, 0.f));
}

// ---------------------------------------------------------------------------
// bf16 MFMA GEMM body: C[M,N](ldc,bf16) = act(A[M,K]bf16 @ W[K,N] + bias_f32)
// Tile 64x128, 4 waves (each 64x32), BK=32, K mult of 32, no guards.
// W supplied TRANSPOSED: Wt[n][k]. LDS rows padded +8 u16.
// ---------------------------------------------------------------------------
__device__ __forceinline__ void mfma_gemm_body(
    const u16* __restrict__ A, const u16* __restrict__ Wt,
    const float* __restrict__ bias, u16* __restrict__ C,
    int K, int ldc, int act, int bx, int by,
    u16 (*As)[40], u16 (*Bs)[40])
{
  const int tid = threadIdx.x;
  const int wid = tid >> 6, lane = tid & 63;
  const int lr = lane & 15, lg = lane >> 4;
  const int brow = by * 64, bcol = bx * 128;

  f32x4 acc[4][2] = {};

  const int ar = tid >> 2, ac = (tid & 3) * 8;
  const u16* Arow  = A  + (size_t)(brow + ar) * K + ac;
  const u16* Brow0 = Wt + (size_t)(bcol + ar) * K + ac;
  const u16* Brow1 = Wt + (size_t)(bcol + 64 + ar) * K + ac;

  for (int k0 = 0; k0 < K; k0 += 32) {
    uint4 va  = *(const uint4*)(Arow  + k0);
    uint4 vb0 = *(const uint4*)(Brow0 + k0);
    uint4 vb1 = *(const uint4*)(Brow1 + k0);
    *(uint4*)&As[ar][ac]      = va;
    *(uint4*)&Bs[ar][ac]      = vb0;
    *(uint4*)&Bs[64 + ar][ac] = vb1;
    __syncthreads();

    bf16x8 af[4], bfr[2];
#pragma unroll
    for (int i = 0; i < 4; ++i)
      af[i] = *(const bf16x8*)&As[i*16 + lr][lg*8];
#pragma unroll
    for (int j = 0; j < 2; ++j)
      bfr[j] = *(const bf16x8*)&Bs[wid*32 + j*16 + lr][lg*8];
#pragma unroll
    for (int i = 0; i < 4; ++i)
#pragma unroll
      for (int j = 0; j < 2; ++j)
        acc[i][j] = __builtin_amdgcn_mfma_f32_16x16x32_bf16(
            af[i], bfr[j], acc[i][j], 0, 0, 0);
    __syncthreads();
  }

  // C/D layout: col=lane&15, row=(lane>>4)*4+reg
#pragma unroll
  for (int i = 0; i < 4; ++i) {
#pragma unroll
    for (int j = 0; j < 2; ++j) {
      int col = bcol + wid*32 + j*16 + lr;
      float bv = bias[col];
#pragma unroll
      for (int r = 0; r < 4; ++r) {
        int row = brow + i*16 + lg*4 + r;
        float v = acc[i][j][r] + bv;
        if (act) v = fmaxf(v, 0.f);
        C[(size_t)row * ldc + col] = f2bf(v);
      }
    }
  }
}

__global__ __launch_bounds__(256) void gemm_kernel(
    const u16* __restrict__ A, const u16* __restrict__ Wt,
    const float* __restrict__ bias, u16* __restrict__ C,
    int K, int Nc, int ldc, int act)
{
  __shared__ __align__(16) u16 As[64][40];
  __shared__ __align__(16) u16 Bs[128][40];
  int nbx = Nc >> 7;
  mfma_gemm_body(A, Wt, bias, C, K, ldc, act,
                 blockIdx.x % nbx, blockIdx.x / nbx, As, Bs);
}

// [0,64) FPS3 single-wave; rest = GEMM (l4)
__global__ __launch_bounds__(256) void fps3_gemm_kernel(
    const float* __restrict__ nx2, int* __restrict__ idx3,
    const u16* __restrict__ A, const u16* __restrict__ Wt,
    const float* __restrict__ bias, u16* __restrict__ C,
    int K, int Nc, int ldc, int act)
{
  __shared__ __align__(16) u16 As[64][40];
  __shared__ __align__(16) u16 Bs[128][40];
  __shared__ float pts[4 * 64 * 3];
  if (blockIdx.x < BB) {
    if (threadIdx.x >= 64) return;
    fps_wave<4>(nx2 + (size_t)blockIdx.x*250*3, 250, 125,
                idx3 + blockIdx.x*125, nullptr, pts);
    return;
  }
  int blk = blockIdx.x - BB;
  int nbx = Nc >> 7;
  mfma_gemm_body(A, Wt, bias, C, K, ldc, act, blk % nbx, blk / nbx, As, Bs);
}

// gather nf2 + cat2-fix fused: [0,gather_blocks) dst[b,s,:]=src[b,idx[b,s],:];
// trailing blocks write cat2 coords (cols 0..2) + zero pad (387..415).
// The l6 GEMM (later launch) writes cols 3..386 -> no same-dword concurrency.
__global__ __launch_bounds__(256) void gatherb_cat2fix_kernel(
    const u16* __restrict__ src, const int* __restrict__ idx,
    u16* __restrict__ dst, int Ss, int Sd, int C, int gather_blocks,
    const float* __restrict__ nx2, u16* __restrict__ cat2, int rows)
{
  if ((int)blockIdx.x >= gather_blocks) {
    int r = ((int)blockIdx.x - gather_blocks) * 256 + threadIdx.x;
    if (r < rows) {
      u16* row = cat2 + (size_t)r * 416;
      row[0] = f2bf(nx2[r*3+0]);
      row[1] = f2bf(nx2[r*3+1]);
      row[2] = f2bf(nx2[r*3+2]);
#pragma unroll
      for (int c = 387; c < 416; ++c) row[c] = 0;
    }
    return;
  }
  int i = blockIdx.x * 256 + threadIdx.x;
  int C8 = C >> 3;
  int total = BB * Sd * C8;
  if (i >= total) return;
  int c = i % C8, t = i / C8, s = t % Sd, b = t / Sd;
  int p = idx[b*Sd + s];
  *(uint4*)&dst[(size_t)i * 8] =
      *(const uint4*)&src[(size_t)(b*Ss + p) * C + c*8];
}

// plain gather (bf16 rows, 16B chunks)
__global__ __launch_bounds__(256) void gatherb_kernel(
    const u16* __restrict__ src, const int* __restrict__ idx,
    u16* __restrict__ dst, int Ss, int Sd, int C)
{
  int i = blockIdx.x * 256 + threadIdx.x;
  int C8 = C >> 3;
  int total = BB * Sd * C8;
  if (i >= total) return;
  int c = i % C8, t = i / C8, s = t % Sd, b = t / Sd;
  int p = idx[b*Sd + s];
  *(uint4*)&dst[(size_t)i * 8] =
      *(const uint4*)&src[(size_t)(b*Ss + p) * C + c*8];
}

// out[b,n] = max_s l8[b,s,n] (bf16 -> f32)
__global__ __launch_bounds__(256) void maxpool_kernel(
    const u16* __restrict__ l8, float* __restrict__ out)
{
  int i = blockIdx.x * 256 + threadIdx.x;
  if (i >= BB * 512) return;
  int b = i >> 9, n = i & 511;
  const u16* p = l8 + (size_t)b * 125 * 512 + n;
  float m = bf2f(p[0]);
  for (int s = 1; s < 125; ++s) m = fmaxf(m, bf2f(p[(size_t)s * 512]));
  out[i] = m;
}

// ---------------------------------------------------------------------------
extern "C" void kernel_launch(void* const* d_in, const int* in_sizes, int n_in,
                              void* d_out, int out_size, void* d_ws, size_t ws_size,
                              hipStream_t stream)
{
  const float* x    = (const float*)d_in[0];
  const float* cw1  = (const float*)d_in[1];
  const float* cb1  = (const float*)d_in[2];
  const float* cw2  = (const float*)d_in[3];
  const float* cb2  = (const float*)d_in[4];
  const float* w1   = (const float*)d_in[5];
  const float* b1   = (const float*)d_in[6];
  const float* w2   = (const float*)d_in[7];
  const float* b2   = (const float*)d_in[8];
  const float* w3   = (const float*)d_in[9];
  const float* b3   = (const float*)d_in[10];
  const float* w4   = (const float*)d_in[11];
  const float* b4   = (const float*)d_in[12];
  const float* w5   = (const float*)d_in[13];
  const float* b5   = (const float*)d_in[14];
  const float* w6   = (const float*)d_in[15];
  const float* b6   = (const float*)d_in[16];
  const float* pc1w = (const float*)d_in[17];
  const float* pc1b = (const float*)d_in[18];
  const float* pc2w = (const float*)d_in[19];
  const float* pc2b = (const float*)d_in[20];

  float* out      = (float*)d_out;          // (64,512)
  float* conf_out = out + 64*512;           // (64,4096,1)

  char* ws = (char*)d_ws;
  size_t off = 0;
  auto alloc = [&](size_t bytes) -> void* {
    void* p = ws + off;
    off = (off + bytes + 255) & ~(size_t)255;
    return p;
  };
  int*   idx1 = (int*)alloc((size_t)BB*500*4);
  int*   idx2 = (int*)alloc((size_t)BB*250*4);
  int*   idx3 = (int*)alloc((size_t)BB*125*4);
  float* nx1  = (float*)alloc((size_t)BB*500*3*4);
  float* nx2  = (float*)alloc((size_t)BB*250*3*4);
  u16* wt1  = (u16*)alloc((size_t)256*256*2);   // pc1w^T           [256][256]
  u16* wt3  = (u16*)alloc((size_t)256*288*2);   // w3^T  K 259->288 [256][288]
  u16* wt4  = (u16*)alloc((size_t)384*256*2);   // w4^T             [384][256]
  u16* wtp2 = (u16*)alloc((size_t)384*384*2);   // pc2w^T           [384][384]
  u16* wt5  = (u16*)alloc((size_t)384*416*2);   // w5^T  K 387->416 [384][416]
  u16* wt6  = (u16*)alloc((size_t)512*384*2);   // w6^T             [512][384]
  u16* P1 = (u16*)alloc((size_t)32000*256*2);   // nf1 -> l4 -> cat2 -> l8
  u16* P2 = (u16*)alloc((size_t)32000*288*2);   // cat1 -> nf2 -> l7
  u16* P3 = (u16*)alloc((size_t)32000*384*2);   // l5 -> nf3
  (void)ws_size; (void)in_sizes; (void)n_in; (void)out_size;

  // L1: FPS1 + conf + weight transpose (hidden under FPS1)
  fps1_conf_wtx_kernel<<<BB + 1024 + 362, 256, 0, stream>>>(
      x, cw1, cb1, cw2, cb2, pc1w, w3, w4, pc2w, w5, w6,
      idx1, nx1, conf_out, wt1, wt3, wt4, wtp2, wt5, wt6);

  // L2: FPS2 + selfeat -> nf1 (P1) + cat1 coord/pad fix (P2)
  fps2_selfeat_cat1fix_kernel<<<BB + 8000 + 125, 256, 0, stream>>>(
      x, nx1, idx1, cw1, cb1, cw2, cb2, w1, b1, w2, b2, idx2, nx2, P1, P2);

  // L3: l3 = nf1 @ pc1w + pc1b -> cat1 cols 3.. (P2, ld 288)
  gemm_kernel<<<1000, 256, 0, stream>>>(P1, wt1, pc1b, P2 + 3, 256, 256, 288, 0);

  // L4: FPS3 + l4 = relu(cat1 @ w3 + b3) -> P1 [32000][256]
  fps3_gemm_kernel<<<BB + 1000, 256, 0, stream>>>(
      nx2, idx3, P2, wt3, b3, P1, 288, 256, 256, 1);

  // L5: l5 = relu(l4 @ w4 + b4) -> P3 [32000][384]
  gemm_kernel<<<1500, 256, 0, stream>>>(P1, wt4, b4, P3, 256, 384, 384, 1);

  // L6: nf2 = l5[idx2] -> P2 [16000][384] + cat2 coord/pad fix (P1, ld 416)
  gatherb_cat2fix_kernel<<<3000 + 63, 256, 0, stream>>>(
      P3, idx2, P2, 500, 250, 384, 3000, nx2, P1, 16000);

  // L7: l6 = nf2 @ pc2w + pc2b -> cat2 cols 3.. (P1, ld 416)
  gemm_kernel<<<750, 256, 0, stream>>>(P2, wtp2, pc2b, P1 + 3, 384, 384, 416, 0);

  // L8: l7 = relu(cat2 @ w5 + b5) -> P2 [16000][384]
  gemm_kernel<<<750, 256, 0, stream>>>(P1, wt5, b5, P2, 416, 384, 384, 1);

  // L9: nf3 = l7[idx3] -> P3 [8000][384]
  gatherb_kernel<<<1500, 256, 0, stream>>>(P2, idx3, P3, 250, 125, 384);

  // L10: l8 = relu(nf3 @ w6 + b6) -> P1 [8000][512]
  gemm_kernel<<<500, 256, 0, stream>>>(P3, wt6, b6, P1, 384, 512, 512, 1);

  // L11: out = max over s (bf16 -> f32)
  maxpool_kernel<<<128, 256, 0, stream>>>(P1, out);
}

// Round 6
// 602.224 us; speedup vs baseline: 2.3484x; 1.1011x over previous
//
#include <hip/hip_runtime.h>
#include <hip/hip_bf16.h>
#include <cstdint>
#include <cstddef>

#define BB 64
#define NN 4096

typedef short bf16x8 __attribute__((ext_vector_type(8)));
typedef float f32x4 __attribute__((ext_vector_type(4)));
typedef unsigned short u16;
typedef unsigned int u32;

__device__ __forceinline__ u16 f2bf(float f) {
  __hip_bfloat16 h = __float2bfloat16(f);   // RTNE
  return *reinterpret_cast<u16*>(&h);
}
__device__ __forceinline__ float bf2f(u16 u) {
  return __uint_as_float((u32)u << 16);
}

// ---------------------------------------------------------------------------
// Forced-IEEE squared distance ((dx*dx + dy*dy) + dz*dz) -> bit-exact argmax.
// ---------------------------------------------------------------------------
__device__ __forceinline__ float sqdist(float px, float py, float pz,
                                        float cx, float cy, float cz) {
  float dx = px - cx, dy = py - cy, dz = pz - cz;
  return __fadd_rn(__fadd_rn(__fmul_rn(dx, dx), __fmul_rn(dy, dy)),
                   __fmul_rn(dz, dz));
}

__device__ __forceinline__ unsigned long long u64max(unsigned long long a,
                                                    unsigned long long b) {
  return a > b ? a : b;
}

// ---------------------------------------------------------------------------
// DPP-based wave argmax: u64 key (dist_bits<<32 | ~idx), max lands in lane 63.
// All-VALU (no LDS pipe): ~20 cy/level vs ~120 cy for ds_swizzle shfl.
// Canonical GCN reduce: row_shr 1/2/4/8, then bcast15 (rows 1,3), bcast31
// (rows 2,3). old=own + bound_ctrl=false => masked/invalid lanes no-op.
// ---------------------------------------------------------------------------
template<int CTRL, int RM>
__device__ __forceinline__ void dpp_max_step(u32& hi, u32& lo) {
  u32 ohi = (u32)__builtin_amdgcn_update_dpp((int)hi, (int)hi, CTRL, RM, 0xf, false);
  u32 olo = (u32)__builtin_amdgcn_update_dpp((int)lo, (int)lo, CTRL, RM, 0xf, false);
  bool gt = (ohi > hi) || ((ohi == hi) && (olo > lo));
  hi = gt ? ohi : hi;
  lo = gt ? olo : lo;
}

__device__ __forceinline__ void wave_argmax_to_lane63(u32& hi, u32& lo) {
  dpp_max_step<0x111, 0xf>(hi, lo);   // row_shr:1
  dpp_max_step<0x112, 0xf>(hi, lo);   // row_shr:2
  dpp_max_step<0x114, 0xf>(hi, lo);   // row_shr:4
  dpp_max_step<0x118, 0xf>(hi, lo);   // row_shr:8  -> lane15/31/47/63 = row max
  dpp_max_step<0x142, 0xa>(hi, lo);   // bcast15 -> rows 1,3
  dpp_max_step<0x143, 0xc>(hi, lo);   // bcast31 -> rows 2,3; lane63 = wave max
}

// ---------------------------------------------------------------------------
// Single-wave FPS (n <= NPER*64). Points in registers; LDS only for the
// uniform-address centroid broadcast. No barriers (only wave 0 runs this).
// OOB slots: coords=0, dst=0 -> key (0, ~bigidx) can never win (real pts win
// ties via smaller index; all-zero case picks idx 0 = numpy argmax).
// ---------------------------------------------------------------------------
template<int NPER>
__device__ void fps_wave(const float* __restrict__ xb, int n, int npoint,
                         int* __restrict__ idx_out, float* __restrict__ sel_out,
                         float* pts)
{
  const int lane = threadIdx.x;
  for (int i = lane; i < n * 3; i += 64) pts[i] = xb[i];
  for (int i = n * 3 + lane; i < NPER * 64 * 3; i += 64) pts[i] = 0.f;

  float px[NPER], py[NPER], pz[NPER], dst[NPER];
#pragma unroll
  for (int k = 0; k < NPER; ++k) {
    int i = k * 64 + lane;
    px[k] = pts[i*3+0]; py[k] = pts[i*3+1]; pz[k] = pts[i*3+2];
    dst[k] = (i < n) ? 1e10f : 0.f;
  }

  int far = 0;
  float cx = pts[0], cy = pts[1], cz = pts[2];

  for (int it = 0; it < npoint; ++it) {
    if (lane == 0) {
      idx_out[it] = far;
      if (sel_out) {
        sel_out[it*3+0] = cx; sel_out[it*3+1] = cy; sel_out[it*3+2] = cz;
      }
    }
    float bestd = -1.f; int besti = 0;
#pragma unroll
    for (int k = 0; k < NPER; ++k) {
      float nd = fminf(dst[k], sqdist(px[k], py[k], pz[k], cx, cy, cz));
      dst[k] = nd;
      if (nd > bestd) { bestd = nd; besti = k * 64 + lane; }
    }
    u32 hi = __float_as_uint(bestd);
    u32 lo = 0xFFFFFFFFu - (u32)besti;
    wave_argmax_to_lane63(hi, lo);
    far = (int)(0xFFFFFFFFu - (u32)__builtin_amdgcn_readlane((int)lo, 63));
    cx = pts[far*3+0]; cy = pts[far*3+1]; cz = pts[far*3+2];
  }
}

// ---------------------------------------------------------------------------
// Kernel A: [0,64) FPS1; [64,1088) conf MLP; [1088,1450) weight transpose+pad
// to bf16 via uint4 stores (16B per thread -> no cross-block dword sharing).
// ---------------------------------------------------------------------------
__global__ __launch_bounds__(256) void fps1_conf_wtx_kernel(
    const float* __restrict__ x,
    const float* __restrict__ cw1, const float* __restrict__ cb1,
    const float* __restrict__ cw2, const float* __restrict__ cb2,
    const float* __restrict__ pc1w, const float* __restrict__ w3,
    const float* __restrict__ w4,  const float* __restrict__ pc2w,
    const float* __restrict__ w5,  const float* __restrict__ w6,
    int* __restrict__ idx1, float* __restrict__ nx1,
    float* __restrict__ conf_out,
    u16* wt1, u16* wt3, u16* wt4, u16* wtp2, u16* wt5, u16* wt6)
{
  if (blockIdx.x >= BB + 1024) {
    // ---- weight transpose + K-pad, 8 u16 per thread (one uint4 store) ----
    int s = (blockIdx.x - (BB + 1024)) * 256 + threadIdx.x;
    const float* src; u16* dst; int N, Ks, Kp;
    if      (s < 8192)  { dst=wt1;  src=pc1w; N=256; Ks=256; Kp=256; }
    else if (s < 17408) { dst=wt3;  src=w3;   N=256; Ks=259; Kp=288; s -= 8192; }
    else if (s < 29696) { dst=wt4;  src=w4;   N=384; Ks=256; Kp=256; s -= 17408; }
    else if (s < 48128) { dst=wtp2; src=pc2w; N=384; Ks=384; Kp=384; s -= 29696; }
    else if (s < 68096) { dst=wt5;  src=w5;   N=384; Ks=387; Kp=416; s -= 48128; }
    else                { dst=wt6;  src=w6;   N=512; Ks=384; Kp=384; s -= 68096; }
    int e0 = s * 8;
    int n = e0 / Kp, k0 = e0 % Kp;      // Kp % 8 == 0 -> row-constant n
    u16 tmp[8];
#pragma unroll
    for (int j = 0; j < 8; ++j) {
      int k = k0 + j;
      tmp[j] = f2bf(k < Ks ? src[k*N + n] : 0.f);
    }
    *(uint4*)&dst[e0] = *(const uint4*)tmp;
    return;
  }
  if (blockIdx.x >= BB) {
    // ---- conf MLP (exact f32, graded output 1) ----
    int i = (blockIdx.x - BB) * 256 + threadIdx.x;
    if (i < BB * NN) {
      float x0 = x[i*3+0], x1 = x[i*3+1], x2 = x[i*3+2];
      float acc = cb2[0];
#pragma unroll
      for (int j = 0; j < 64; ++j) {
        float h = fmaxf(x0*cw1[j] + x1*cw1[64+j] + x2*cw1[128+j] + cb1[j], 0.f);
        acc += h * cw2[j];
      }
      conf_out[i] = 1.f / (1.f + expf(-acc));
    }
    return;
  }

  // ---- FPS1: 256 thr, 16 pts/thread in registers, 1 barrier/iter,
  //      DPP wave reduce + cross-wave LDS combine ----
  constexpr int NPER = NN / 256;
  __shared__ float pts[NN * 3];
  __shared__ unsigned long long sh_pk[2][4];
  const int b = blockIdx.x, tid = threadIdx.x;
  const float* xb = x + (size_t)b * NN * 3;

  for (int i = tid; i < NN * 3; i += 256) pts[i] = xb[i];
  __syncthreads();

  float px[NPER], py[NPER], pz[NPER], dstv[NPER];
#pragma unroll
  for (int k = 0; k < NPER; ++k) {
    int i = k * 256 + tid;
    px[k] = pts[i*3+0]; py[k] = pts[i*3+1]; pz[k] = pts[i*3+2];
    dstv[k] = 1e10f;
  }

  int far = 0;
  float cx = pts[0], cy = pts[1], cz = pts[2];

  for (int it = 0; it < 500; ++it) {
    if (tid == 0) {
      idx1[b*500 + it] = far;
      nx1[(b*500+it)*3+0] = cx; nx1[(b*500+it)*3+1] = cy; nx1[(b*500+it)*3+2] = cz;
    }
    float bestd = -1.f; int besti = 0;
#pragma unroll
    for (int k = 0; k < NPER; ++k) {
      int i = k * 256 + tid;
      float nd = fminf(dstv[k], sqdist(px[k], py[k], pz[k], cx, cy, cz));
      dstv[k] = nd;
      if (nd > bestd) { bestd = nd; besti = i; }   // 4096 = 16*256, no guard
    }
    u32 hi = __float_as_uint(bestd);
    u32 lo = 0xFFFFFFFFu - (u32)besti;
    wave_argmax_to_lane63(hi, lo);
    if ((tid & 63) == 63)
      sh_pk[it & 1][tid >> 6] = ((unsigned long long)hi << 32) | lo;
    __syncthreads();
    unsigned long long m = u64max(u64max(sh_pk[it&1][0], sh_pk[it&1][1]),
                                  u64max(sh_pk[it&1][2], sh_pk[it&1][3]));
    far = (int)(0xFFFFFFFFu - (u32)(m & 0xFFFFFFFFull));
    cx = pts[far*3+0]; cy = pts[far*3+1]; cz = pts[far*3+2];
  }
}

// ---------------------------------------------------------------------------
// Kernel B: [0,64) FPS2 single-wave; [64,8064) selfeat -> nf1 bf16;
// [8064,8189) cat1-fix (coords cols 0..2 + zero pad 259..287).
// ---------------------------------------------------------------------------
__global__ __launch_bounds__(256) void fps2_selfeat_cat1fix_kernel(
    const float* __restrict__ x, const float* __restrict__ nx1,
    const int* __restrict__ idx1,
    const float* __restrict__ cw1, const float* __restrict__ cb1,
    const float* __restrict__ cw2, const float* __restrict__ cb2,
    const float* __restrict__ w1, const float* __restrict__ b1,
    const float* __restrict__ w2, const float* __restrict__ b2,
    int* __restrict__ idx2, float* __restrict__ nx2,
    u16* __restrict__ nf1, u16* __restrict__ cat1)
{
  __shared__ float pts[8 * 64 * 3];
  __shared__ float l1s[4][64];

  if (blockIdx.x < BB) {
    if (threadIdx.x >= 64) return;
    int b = blockIdx.x;
    fps_wave<8>(nx1 + (size_t)b*500*3, 500, 250,
                idx2 + b*250, nx2 + (size_t)b*250*3, pts);
    return;
  }
  if (blockIdx.x >= BB + 8000) {
    int r = (blockIdx.x - (BB + 8000)) * 256 + threadIdx.x;  // < 32000
    u16* row = cat1 + (size_t)r * 288;
    row[0] = f2bf(nx1[r*3+0]);
    row[1] = f2bf(nx1[r*3+1]);
    row[2] = f2bf(nx1[r*3+2]);
#pragma unroll
    for (int c = 259; c < 288; ++c) row[c] = 0;
    return;
  }

  int wid  = threadIdx.x >> 6;
  int lane = threadIdx.x & 63;
  int gw   = (blockIdx.x - BB) * 4 + wid;      // [0, 32000)
  int b = gw / 500, s = gw % 500;
  int p = idx1[b*500 + s];
  const float* xp = x + ((size_t)b * NN + p) * 3;
  float x0 = xp[0], x1 = xp[1], x2 = xp[2];

  float h = fmaxf(x0*cw1[lane] + x1*cw1[64+lane] + x2*cw1[128+lane] + cb1[lane], 0.f);
  float part = h * cw2[lane];
#pragma unroll
  for (int o = 32; o > 0; o >>= 1) part += __shfl_xor(part, o);
  float conf = 1.f / (1.f + expf(-(part + cb2[0])));

  float l1v = fmaxf(conf*w1[lane] + x0*w1[64+lane] + x1*w1[128+lane]
                    + x2*w1[192+lane] + b1[lane], 0.f);
  l1s[wid][lane] = l1v;
  __syncthreads();

  float a0 = b2[lane], a1 = b2[64+lane], a2 = b2[128+lane], a3 = b2[192+lane];
#pragma unroll
  for (int k = 0; k < 64; ++k) {
    float lv = l1s[wid][k];
    const float* wr = w2 + k*256;
    a0 += lv * wr[lane];
    a1 += lv * wr[64+lane];
    a2 += lv * wr[128+lane];
    a3 += lv * wr[192+lane];
  }
  u16* o = nf1 + (size_t)gw * 256;
  o[lane]     = f2bf(fmaxf(a0, 0.f));
  o[64+lane]  = f2bf(fmaxf(a1, 0.f));
  o[128+lane] = f2bf(fmaxf(a2, 0.f));
  o[192+lane] = f2bf(fmaxf(a3, 0.f));
}

// ---------------------------------------------------------------------------
// bf16 MFMA GEMM body: C[M,N](ldc,bf16) = act(A[M,K]bf16 @ W[K,N] + bias_f32)
// Tile 64x128, 4 waves (each 64x32), BK=32, K mult of 32, no guards.
// W supplied TRANSPOSED: Wt[n][k]. LDS rows padded +8 u16.
// ---------------------------------------------------------------------------
__device__ __forceinline__ void mfma_gemm_body(
    const u16* __restrict__ A, const u16* __restrict__ Wt,
    const float* __restrict__ bias, u16* __restrict__ C,
    int K, int ldc, int act, int bx, int by,
    u16 (*As)[40], u16 (*Bs)[40])
{
  const int tid = threadIdx.x;
  const int wid = tid >> 6, lane = tid & 63;
  const int lr = lane & 15, lg = lane >> 4;
  const int brow = by * 64, bcol = bx * 128;

  f32x4 acc[4][2] = {};

  const int ar = tid >> 2, ac = (tid & 3) * 8;
  const u16* Arow  = A  + (size_t)(brow + ar) * K + ac;
  const u16* Brow0 = Wt + (size_t)(bcol + ar) * K + ac;
  const u16* Brow1 = Wt + (size_t)(bcol + 64 + ar) * K + ac;

  for (int k0 = 0; k0 < K; k0 += 32) {
    uint4 va  = *(const uint4*)(Arow  + k0);
    uint4 vb0 = *(const uint4*)(Brow0 + k0);
    uint4 vb1 = *(const uint4*)(Brow1 + k0);
    *(uint4*)&As[ar][ac]      = va;
    *(uint4*)&Bs[ar][ac]      = vb0;
    *(uint4*)&Bs[64 + ar][ac] = vb1;
    __syncthreads();

    bf16x8 af[4], bfr[2];
#pragma unroll
    for (int i = 0; i < 4; ++i)
      af[i] = *(const bf16x8*)&As[i*16 + lr][lg*8];
#pragma unroll
    for (int j = 0; j < 2; ++j)
      bfr[j] = *(const bf16x8*)&Bs[wid*32 + j*16 + lr][lg*8];
#pragma unroll
    for (int i = 0; i < 4; ++i)
#pragma unroll
      for (int j = 0; j < 2; ++j)
        acc[i][j] = __builtin_amdgcn_mfma_f32_16x16x32_bf16(
            af[i], bfr[j], acc[i][j], 0, 0, 0);
    __syncthreads();
  }

  // C/D layout: col=lane&15, row=(lane>>4)*4+reg
#pragma unroll
  for (int i = 0; i < 4; ++i) {
#pragma unroll
    for (int j = 0; j < 2; ++j) {
      int col = bcol + wid*32 + j*16 + lr;
      float bv = bias[col];
#pragma unroll
      for (int r = 0; r < 4; ++r) {
        int row = brow + i*16 + lg*4 + r;
        float v = acc[i][j][r] + bv;
        if (act) v = fmaxf(v, 0.f);
        C[(size_t)row * ldc + col] = f2bf(v);
      }
    }
  }
}

__global__ __launch_bounds__(256) void gemm_kernel(
    const u16* __restrict__ A, const u16* __restrict__ Wt,
    const float* __restrict__ bias, u16* __restrict__ C,
    int K, int Nc, int ldc, int act)
{
  __shared__ __align__(16) u16 As[64][40];
  __shared__ __align__(16) u16 Bs[128][40];
  int nbx = Nc >> 7;
  mfma_gemm_body(A, Wt, bias, C, K, ldc, act,
                 blockIdx.x % nbx, blockIdx.x / nbx, As, Bs);
}

// [0,64) FPS3 single-wave; rest = GEMM (l4)
__global__ __launch_bounds__(256) void fps3_gemm_kernel(
    const float* __restrict__ nx2, int* __restrict__ idx3,
    const u16* __restrict__ A, const u16* __restrict__ Wt,
    const float* __restrict__ bias, u16* __restrict__ C,
    int K, int Nc, int ldc, int act)
{
  __shared__ __align__(16) u16 As[64][40];
  __shared__ __align__(16) u16 Bs[128][40];
  __shared__ float pts[4 * 64 * 3];
  if (blockIdx.x < BB) {
    if (threadIdx.x >= 64) return;
    fps_wave<4>(nx2 + (size_t)blockIdx.x*250*3, 250, 125,
                idx3 + blockIdx.x*125, nullptr, pts);
    return;
  }
  int blk = blockIdx.x - BB;
  int nbx = Nc >> 7;
  mfma_gemm_body(A, Wt, bias, C, K, ldc, act, blk % nbx, blk / nbx, As, Bs);
}

// gather nf2 + cat2-fix fused
__global__ __launch_bounds__(256) void gatherb_cat2fix_kernel(
    const u16* __restrict__ src, const int* __restrict__ idx,
    u16* __restrict__ dst, int Ss, int Sd, int C, int gather_blocks,
    const float* __restrict__ nx2, u16* __restrict__ cat2, int rows)
{
  if ((int)blockIdx.x >= gather_blocks) {
    int r = ((int)blockIdx.x - gather_blocks) * 256 + threadIdx.x;
    if (r < rows) {
      u16* row = cat2 + (size_t)r * 416;
      row[0] = f2bf(nx2[r*3+0]);
      row[1] = f2bf(nx2[r*3+1]);
      row[2] = f2bf(nx2[r*3+2]);
#pragma unroll
      for (int c = 387; c < 416; ++c) row[c] = 0;
    }
    return;
  }
  int i = blockIdx.x * 256 + threadIdx.x;
  int C8 = C >> 3;
  int total = BB * Sd * C8;
  if (i >= total) return;
  int c = i % C8, t = i / C8, s = t % Sd, b = t / Sd;
  int p = idx[b*Sd + s];
  *(uint4*)&dst[(size_t)i * 8] =
      *(const uint4*)&src[(size_t)(b*Ss + p) * C + c*8];
}

// plain gather (bf16 rows, 16B chunks)
__global__ __launch_bounds__(256) void gatherb_kernel(
    const u16* __restrict__ src, const int* __restrict__ idx,
    u16* __restrict__ dst, int Ss, int Sd, int C)
{
  int i = blockIdx.x * 256 + threadIdx.x;
  int C8 = C >> 3;
  int total = BB * Sd * C8;
  if (i >= total) return;
  int c = i % C8, t = i / C8, s = t % Sd, b = t / Sd;
  int p = idx[b*Sd + s];
  *(uint4*)&dst[(size_t)i * 8] =
      *(const uint4*)&src[(size_t)(b*Ss + p) * C + c*8];
}

// out[b,n] = max_s l8[b,s,n] (bf16 -> f32)
__global__ __launch_bounds__(256) void maxpool_kernel(
    const u16* __restrict__ l8, float* __restrict__ out)
{
  int i = blockIdx.x * 256 + threadIdx.x;
  if (i >= BB * 512) return;
  int b = i >> 9, n = i & 511;
  const u16* p = l8 + (size_t)b * 125 * 512 + n;
  float m = bf2f(p[0]);
  for (int s = 1; s < 125; ++s) m = fmaxf(m, bf2f(p[(size_t)s * 512]));
  out[i] = m;
}

// ---------------------------------------------------------------------------
extern "C" void kernel_launch(void* const* d_in, const int* in_sizes, int n_in,
                              void* d_out, int out_size, void* d_ws, size_t ws_size,
                              hipStream_t stream)
{
  const float* x    = (const float*)d_in[0];
  const float* cw1  = (const float*)d_in[1];
  const float* cb1  = (const float*)d_in[2];
  const float* cw2  = (const float*)d_in[3];
  const float* cb2  = (const float*)d_in[4];
  const float* w1   = (const float*)d_in[5];
  const float* b1   = (const float*)d_in[6];
  const float* w2   = (const float*)d_in[7];
  const float* b2   = (const float*)d_in[8];
  const float* w3   = (const float*)d_in[9];
  const float* b3   = (const float*)d_in[10];
  const float* w4   = (const float*)d_in[11];
  const float* b4   = (const float*)d_in[12];
  const float* w5   = (const float*)d_in[13];
  const float* b5   = (const float*)d_in[14];
  const float* w6   = (const float*)d_in[15];
  const float* b6   = (const float*)d_in[16];
  const float* pc1w = (const float*)d_in[17];
  const float* pc1b = (const float*)d_in[18];
  const float* pc2w = (const float*)d_in[19];
  const float* pc2b = (const float*)d_in[20];

  float* out      = (float*)d_out;          // (64,512)
  float* conf_out = out + 64*512;           // (64,4096,1)

  char* ws = (char*)d_ws;
  size_t off = 0;
  auto alloc = [&](size_t bytes) -> void* {
    void* p = ws + off;
    off = (off + bytes + 255) & ~(size_t)255;
    return p;
  };
  int*   idx1 = (int*)alloc((size_t)BB*500*4);
  int*   idx2 = (int*)alloc((size_t)BB*250*4);
  int*   idx3 = (int*)alloc((size_t)BB*125*4);
  float* nx1  = (float*)alloc((size_t)BB*500*3*4);
  float* nx2  = (float*)alloc((size_t)BB*250*3*4);
  u16* wt1  = (u16*)alloc((size_t)256*256*2);   // pc1w^T           [256][256]
  u16* wt3  = (u16*)alloc((size_t)256*288*2);   // w3^T  K 259->288 [256][288]
  u16* wt4  = (u16*)alloc((size_t)384*256*2);   // w4^T             [384][256]
  u16* wtp2 = (u16*)alloc((size_t)384*384*2);   // pc2w^T           [384][384]
  u16* wt5  = (u16*)alloc((size_t)384*416*2);   // w5^T  K 387->416 [384][416]
  u16* wt6  = (u16*)alloc((size_t)512*384*2);   // w6^T             [512][384]
  u16* P1 = (u16*)alloc((size_t)32000*256*2);   // nf1 -> l4 -> cat2 -> l8
  u16* P2 = (u16*)alloc((size_t)32000*288*2);   // cat1 -> nf2 -> l7
  u16* P3 = (u16*)alloc((size_t)32000*384*2);   // l5 -> nf3
  (void)ws_size; (void)in_sizes; (void)n_in; (void)out_size;

  // L1: FPS1 + conf + weight transpose (hidden under FPS1)
  fps1_conf_wtx_kernel<<<BB + 1024 + 362, 256, 0, stream>>>(
      x, cw1, cb1, cw2, cb2, pc1w, w3, w4, pc2w, w5, w6,
      idx1, nx1, conf_out, wt1, wt3, wt4, wtp2, wt5, wt6);

  // L2: FPS2 + selfeat -> nf1 (P1) + cat1 coord/pad fix (P2)
  fps2_selfeat_cat1fix_kernel<<<BB + 8000 + 125, 256, 0, stream>>>(
      x, nx1, idx1, cw1, cb1, cw2, cb2, w1, b1, w2, b2, idx2, nx2, P1, P2);

  // L3: l3 = nf1 @ pc1w + pc1b -> cat1 cols 3.. (P2, ld 288)
  gemm_kernel<<<1000, 256, 0, stream>>>(P1, wt1, pc1b, P2 + 3, 256, 256, 288, 0);

  // L4: FPS3 + l4 = relu(cat1 @ w3 + b3) -> P1 [32000][256]
  fps3_gemm_kernel<<<BB + 1000, 256, 0, stream>>>(
      nx2, idx3, P2, wt3, b3, P1, 288, 256, 256, 1);

  // L5: l5 = relu(l4 @ w4 + b4) -> P3 [32000][384]
  gemm_kernel<<<1500, 256, 0, stream>>>(P1, wt4, b4, P3, 256, 384, 384, 1);

  // L6: nf2 = l5[idx2] -> P2 [16000][384] + cat2 coord/pad fix (P1, ld 416)
  gatherb_cat2fix_kernel<<<3000 + 63, 256, 0, stream>>>(
      P3, idx2, P2, 500, 250, 384, 3000, nx2, P1, 16000);

  // L7: l6 = nf2 @ pc2w + pc2b -> cat2 cols 3.. (P1, ld 416)
  gemm_kernel<<<750, 256, 0, stream>>>(P2, wtp2, pc2b, P1 + 3, 384, 384, 416, 0);

  // L8: l7 = relu(cat2 @ w5 + b5) -> P2 [16000][384]
  gemm_kernel<<<750, 256, 0, stream>>>(P1, wt5, b5, P2, 416, 384, 384, 1);

  // L9: nf3 = l7[idx3] -> P3 [8000][384]
  gatherb_kernel<<<1500, 256, 0, stream>>>(P2, idx3, P3, 250, 125, 384);

  // L10: l8 = relu(nf3 @ w6 + b6) -> P1 [8000][512]
  gemm_kernel<<<500, 256, 0, stream>>>(P3, wt6, b6, P1, 384, 512, 512, 1);

  // L11: out = max over s (bf16 -> f32)
  maxpool_kernel<<<128, 256, 0, stream>>>(P1, out);
}